// Round 10
// baseline (901.670 us; speedup 1.0000x reference)
//
#include <hip/hip_runtime.h>
#include <math.h>

#define KNN 20
// 1/sqrt(1 + 1e-5)
#define BN_INV 0.9999950000374997f

__device__ __forceinline__ unsigned f2o(float f){
    unsigned u = __float_as_uint(f);
    return (u >> 31) ? ~u : (u | 0x80000000u);
}
__device__ __forceinline__ float o2f(unsigned u){
    return __uint_as_float((u >> 31) ? (u & 0x7fffffffu) : ~u);
}
__device__ __forceinline__ float leaky(float v){ return v > 0.f ? v : 0.2f * v; }

// Build feats[B,N,116] = [gfeat(14) | lbs(24) | pose(75) | pad0(3)]; also sq[row]
__global__ __launch_bounds__(128) void build_feats_kernel(
    const float* __restrict__ xyz, const float* __restrict__ scale,
    const float* __restrict__ rot, const float* __restrict__ opac,
    const float* __restrict__ color, const float* __restrict__ pose,
    const float* __restrict__ lbs, float* __restrict__ feats,
    float* __restrict__ sqout, int N)
{
    __shared__ float sred[2];
    int row = blockIdx.x;           // b*N + n
    int b = row / N, n = row % N;
    int c = threadIdx.x;            // 128 threads, write c<116
    float v = 0.f;
    if      (c <   3) v = xyz  [n*3 + c];
    else if (c <   6) v = scale[n*3 + c-3];
    else if (c <  10) v = rot  [n*4 + c-6];
    else if (c <  11) v = opac [n];
    else if (c <  14) v = color[n*3 + c-11];
    else if (c <  38) v = lbs  [n*24 + c-14];
    else if (c < 113) v = pose [b*75 + c-38];
    if (c < 116) feats[(long)row*116 + c] = v;
    float ss = v * v;
    #pragma unroll
    for (int off = 32; off; off >>= 1) ss += __shfl_xor(ss, off);
    if ((c & 63) == 0) sred[c >> 6] = ss;
    __syncthreads();
    if (c == 0) sqout[row] = sred[0] + sred[1];
}

// ---------------- kNN: packed-symmetric Gram + threshold-select top-k ----------------

// Packed upper-triangle grid; KC=32 chunks with register prefetch of next
// chunk (global->reg during compute, reg->LDS after barrier). Accumulation
// order (ascending c) identical -> G bit-identical to previous rounds.
template<int C>
__global__ __launch_bounds__(256, 4) void dist_gemm_kernel(
    const float* __restrict__ x, int N, int CP, float* __restrict__ G)
{
    __shared__ __align__(16) float smem[9216];       // 36864 B
    float (*xi)[36] = (float(*)[36])smem;            // [128][36]
    float (*xj)[36] = (float(*)[36])(smem + 128*36);

    const int q = blockIdx.x;
    int bjt = (int)((sqrtf(8.f*(float)q + 1.f) - 1.f) * 0.5f);
    while ((bjt+1)*(bjt+2)/2 <= q) ++bjt;
    while (bjt*(bjt+1)/2 > q) --bjt;
    const int bit = q - bjt*(bjt+1)/2;               // bi-tile <= bj-tile
    const int bi = bit * 128;
    const int bj = bjt * 128;

    const int b  = blockIdx.z;
    const int t  = threadIdx.x;
    const int tx = t & 15, ty = t >> 4;
    const int CP4 = CP / 4;
    const long base = (long)b * N;
    const float4* xp = (const float4*)x;

    float acc[8][8] = {};
    float4 pa[4], pb[4];

    int c0 = 0;
    int KC4 = ((C < 32) ? C : 32) >> 2;
    #pragma unroll
    for (int s = 0; s < 4; ++s){
        int f = t + 256*s;
        if (f < 128*KC4){
            int r = f / KC4, c4 = f - r*KC4;
            pa[s] = xp[(base + bi + r) * CP4 + c4];
            pb[s] = xp[(base + bj + r) * CP4 + c4];
        }
    }

    for (;;){
        __syncthreads();
        #pragma unroll
        for (int s = 0; s < 4; ++s){
            int f = t + 256*s;
            if (f < 128*KC4){
                int r = f / KC4, c4 = f - r*KC4;
                *(float4*)&xi[r][c4*4] = pa[s];
                *(float4*)&xj[r][c4*4] = pb[s];
            }
        }
        __syncthreads();
        const int KC  = KC4 * 4;
        const int c0n = c0 + 32;
        int KC4n = 0;
        if (c0n < C){
            KC4n = (((C - c0n) < 32) ? (C - c0n) : 32) >> 2;
            #pragma unroll
            for (int s = 0; s < 4; ++s){
                int f = t + 256*s;
                if (f < 128*KC4n){
                    int r = f / KC4n, c4 = f - r*KC4n;
                    pa[s] = xp[(base + bi + r) * CP4 + (c0n >> 2) + c4];
                    pb[s] = xp[(base + bj + r) * CP4 + (c0n >> 2) + c4];
                }
            }
        }
        for (int c = 0; c < KC; c += 4){
            float4 A[8], Bv[8];
            #pragma unroll
            for (int ii = 0; ii < 8; ++ii) A[ii]  = *(const float4*)&xi[ty + 16*ii][c];
            #pragma unroll
            for (int jj = 0; jj < 8; ++jj) Bv[jj] = *(const float4*)&xj[tx + 16*jj][c];
            #pragma unroll
            for (int ii = 0; ii < 8; ++ii)
                #pragma unroll
                for (int jj = 0; jj < 8; ++jj){
                    acc[ii][jj] = fmaf(A[ii].x, Bv[jj].x, acc[ii][jj]);
                    acc[ii][jj] = fmaf(A[ii].y, Bv[jj].y, acc[ii][jj]);
                    acc[ii][jj] = fmaf(A[ii].z, Bv[jj].z, acc[ii][jj]);
                    acc[ii][jj] = fmaf(A[ii].w, Bv[jj].w, acc[ii][jj]);
                }
        }
        if (c0n >= C) break;
        c0 = c0n; KC4 = KC4n;
    }

    // upper tile (coalesced)
    #pragma unroll
    for (int ii = 0; ii < 8; ++ii){
        long rbase = (base + bi + ty + 16*ii) * N + bj;
        #pragma unroll
        for (int jj = 0; jj < 8; ++jj)
            G[rbase + tx + 16*jj] = acc[ii][jj];
    }

    // mirror tile via two 64-row transpose half-passes (values bit-identical)
    if (bi != bj){
        float (*tr)[132] = (float(*)[132])smem;      // 64*132*4 = 33792 B
        #pragma unroll
        for (int h = 0; h < 2; ++h){
            __syncthreads();
            #pragma unroll
            for (int ii = 0; ii < 8; ++ii)
                #pragma unroll
                for (int jj = 4*h; jj < 4*h + 4; ++jj)
                    tr[tx + 16*(jj - 4*h)][ty + 16*ii] = acc[ii][jj];
            __syncthreads();
            const int cc = (t & 31) * 4;
            const int r0 = t >> 5;
            #pragma unroll
            for (int f = 0; f < 8; ++f){
                int r = r0 + 8 * f;
                *(float4*)&G[(base + bj + 64*h + r) * N + bi + cc] = *(const float4*)&tr[r][cc];
            }
        }
    }
}

// Per-row top-20 SET by key u_j = f2o(2*G[i][j] - sq[j]); threshold select.
#define TCAP 256
__global__ __launch_bounds__(256) void topk_kernel(
    const float* __restrict__ G, const float* __restrict__ sq,
    int N, int* __restrict__ idx_out)
{
    __shared__ unsigned smax[256];
    __shared__ unsigned cand_u[TCAP];
    __shared__ int      cand_j[TCAP];
    __shared__ unsigned cand_cnt;
    __shared__ unsigned sTu;

    const int row = blockIdx.x;
    const int b   = row >> 12;
    const int t   = threadIdx.x;
    const float4* g4  = (const float4*)(G  + (long)row * 4096);
    const float4* sq4 = (const float4*)(sq + (long)b   * 4096);

    unsigned u[16];
    #pragma unroll
    for (int qq = 0; qq < 4; ++qq){
        int v4 = t + 256 * qq;
        float4 gg = g4[v4];
        float4 ss = sq4[v4];
        u[4*qq+0] = f2o(fmaf(2.f, gg.x, -ss.x));
        u[4*qq+1] = f2o(fmaf(2.f, gg.y, -ss.y));
        u[4*qq+2] = f2o(fmaf(2.f, gg.z, -ss.z));
        u[4*qq+3] = f2o(fmaf(2.f, gg.w, -ss.w));
    }

    unsigned mu = u[0];
    #pragma unroll
    for (int q = 1; q < 16; ++q) mu = u[q] > mu ? u[q] : mu;
    smax[t] = mu;
    if (t == 0) cand_cnt = 0;
    __syncthreads();

    int rank = 0;
    for (int k = 0; k < 256; ++k){
        unsigned ou = smax[k];
        rank += (ou > mu) || (ou == mu && k < t);
    }
    if (rank == KNN - 1) sTu = mu;
    __syncthreads();
    const unsigned Tu = sTu;

    #pragma unroll
    for (int qq = 0; qq < 4; ++qq)
        #pragma unroll
        for (int m = 0; m < 4; ++m){
            int q = 4*qq + m;
            if (u[q] >= Tu){
                unsigned p = atomicAdd(&cand_cnt, 1u);
                if (p < TCAP){ cand_u[p] = u[q]; cand_j[p] = 4*(t + 256*qq) + m; }
            }
        }
    __syncthreads();
    const int cc = (int)cand_cnt;

    if (cc <= TCAP){
        if (t < cc){
            unsigned cu = cand_u[t]; int cj = cand_j[t];
            int r = 0;
            for (int k = 0; k < cc; ++k){
                unsigned ou = cand_u[k];
                r += (ou > cu) || (ou == cu && cand_j[k] < cj);
            }
            if (r < KNN) idx_out[(long)row * KNN + r] = cj;
        }
    } else {
        __shared__ unsigned rv[4]; __shared__ int ri[4]; __shared__ int gj_;
        unsigned lv = 0u; int lj = 0x7fffffff;
        #pragma unroll
        for (int q = 0; q < 16; ++q)
            if (u[q] > lv){ lv = u[q]; lj = 4*(t + 256*(q>>2)) + (q&3); }
        for (int it = 0; it < KNN; ++it){
            unsigned bv = lv; int bj = lj;
            #pragma unroll
            for (int off = 32; off; off >>= 1){
                unsigned ov = __shfl_xor(bv, off);
                int      oj = __shfl_xor(bj, off);
                if (ov > bv || (ov == bv && oj < bj)){ bv = ov; bj = oj; }
            }
            if ((t & 63) == 0){ rv[t >> 6] = bv; ri[t >> 6] = bj; }
            __syncthreads();
            if (t == 0){
                unsigned fv = rv[0]; int fj = ri[0];
                #pragma unroll
                for (int w = 1; w < 4; ++w)
                    if (rv[w] > fv || (rv[w] == fv && ri[w] < fj)){ fv = rv[w]; fj = ri[w]; }
                gj_ = fj;
                idx_out[(long)row * KNN + it] = fj;
            }
            __syncthreads();
            int fj = gj_;
            if (fj >= 0 && ((fj >> 2) & 255) == t){
                u[((fj >> 10) << 2) | (fj & 3)] = 0u;
                lv = 0u; lj = 0x7fffffff;
                #pragma unroll
                for (int q = 0; q < 16; ++q)
                    if (u[q] > lv){ lv = u[q]; lj = 4*(t + 256*(q>>2)) + (q&3); }
            }
            __syncthreads();
        }
    }
}

// ---------------- EdgeConv as P/Q GEMM + gather-max ----------------

__device__ __forceinline__ void wcat_emit(const float* __restrict__ W, int C, int D,
                                          int i, float* __restrict__ dst)
{
    int TWOD = 2 * D;
    int c = i / TWOD, n = i - c * TWOD;
    float v = 0.f;
    if (c < C) v = (n < D) ? W[c*D + n] : (W[(C + c)*D + (n - D)] - W[c*D + (n - D)]);
    dst[i] = v;
}

__global__ void prep_all_wcat_kernel(
    const float* __restrict__ Wc1, const float* __restrict__ Wc2,
    const float* __restrict__ Wc3, const float* __restrict__ Wc4,
    float* __restrict__ Wcat)
{
    int i = blockIdx.x * 256 + threadIdx.x;
    if      (i <  14848) wcat_emit(Wc1, 113,  64, i,          Wcat);
    else if (i <  23040) wcat_emit(Wc2,  64,  64, i - 14848,  Wcat + 14848);
    else if (i <  39424) wcat_emit(Wc3,  64, 128, i - 23040,  Wcat + 23040);
    else if (i < 104960) wcat_emit(Wc4, 128, 256, i - 39424,  Wcat + 39424);
}

// PQ = X @ Wcat with BN/bias epilogue. 128x128 tiles, KC=32, register prefetch.
// Per-element fmaf chain (ascending c) identical to prior rounds.
__global__ __launch_bounds__(256) void gemm_pq_kernel(
    const float* __restrict__ X, int CP, const float* __restrict__ Wcat,
    const float* __restrict__ g, const float* __restrict__ bias,
    int D, int TWOD, float* __restrict__ PQ)
{
    __shared__ __align__(16) float As[128][36];
    __shared__ __align__(16) float Bs[32][132];
    const int bi = blockIdx.x * 128;
    const int bn = blockIdx.y * 128;
    const int t  = threadIdx.x;
    const int tx = t & 15, ty = t >> 4;
    const int CP4 = CP / 4;
    const float4* xp = (const float4*)X;

    float acc[8][8] = {};
    float4 pa[4], pb[4];

    int c0 = 0;
    int KC4 = ((CP < 32) ? CP : 32) >> 2;
    #pragma unroll
    for (int s = 0; s < 4; ++s){
        int f = t + 256*s;
        if (f < 128*KC4){
            int r = f / KC4, c4 = f - r*KC4;
            pa[s] = xp[(long)(bi + r)*CP4 + c4];
        }
        if (f < 128*KC4){
            int r = f >> 5, c4 = f & 31;
            pb[s] = *(const float4*)&Wcat[(long)r * TWOD + bn + c4*4];
        }
    }

    for (;;){
        __syncthreads();
        #pragma unroll
        for (int s = 0; s < 4; ++s){
            int f = t + 256*s;
            if (f < 128*KC4){
                int r = f / KC4, c4 = f - r*KC4;
                *(float4*)&As[r][c4*4] = pa[s];
            }
            if (f < 128*KC4){
                int r = f >> 5, c4 = f & 31;
                *(float4*)&Bs[r][c4*4] = pb[s];
            }
        }
        __syncthreads();
        const int KC  = KC4 * 4;
        const int c0n = c0 + 32;
        int KC4n = 0;
        if (c0n < CP){
            KC4n = (((CP - c0n) < 32) ? (CP - c0n) : 32) >> 2;
            #pragma unroll
            for (int s = 0; s < 4; ++s){
                int f = t + 256*s;
                if (f < 128*KC4n){
                    int r = f / KC4n, c4 = f - r*KC4n;
                    pa[s] = xp[(long)(bi + r)*CP4 + (c0n >> 2) + c4];
                }
                if (f < 128*KC4n){
                    int r = f >> 5, c4 = f & 31;
                    pb[s] = *(const float4*)&Wcat[(long)(c0n + r) * TWOD + bn + c4*4];
                }
            }
        }
        for (int c = 0; c < KC; c += 4){
            float4 A[8];
            #pragma unroll
            for (int ii = 0; ii < 8; ++ii) A[ii] = *(const float4*)&As[ty + 16*ii][c];
            float Bv0[8], Bv1[8], Bv2[8], Bv3[8];
            #pragma unroll
            for (int jj = 0; jj < 8; ++jj){
                Bv0[jj] = Bs[c+0][tx + 16*jj];
                Bv1[jj] = Bs[c+1][tx + 16*jj];
                Bv2[jj] = Bs[c+2][tx + 16*jj];
                Bv3[jj] = Bs[c+3][tx + 16*jj];
            }
            #pragma unroll
            for (int ii = 0; ii < 8; ++ii)
                #pragma unroll
                for (int jj = 0; jj < 8; ++jj){
                    acc[ii][jj] = fmaf(A[ii].x, Bv0[jj], acc[ii][jj]);
                    acc[ii][jj] = fmaf(A[ii].y, Bv1[jj], acc[ii][jj]);
                    acc[ii][jj] = fmaf(A[ii].z, Bv2[jj], acc[ii][jj]);
                    acc[ii][jj] = fmaf(A[ii].w, Bv3[jj], acc[ii][jj]);
                }
        }
        if (c0n >= CP) break;
        c0 = c0n; KC4 = KC4n;
    }

    #pragma unroll
    for (int jj = 0; jj < 8; ++jj){
        int n = bn + tx + 16*jj;
        int d = (n < D) ? n : n - D;
        float gg = g[d] * BN_INV;
        float bb = (n < D) ? 0.f : bias[d];
        #pragma unroll
        for (int ii = 0; ii < 8; ++ii)
            PQ[(long)(bi + ty + 16*ii) * TWOD + n] = fmaf(acc[ii][jj], gg, bb);
    }
}

// 64x64-tile variant for the small layers (full CU coverage on small grids).
__global__ __launch_bounds__(256) void gemm_pq64_kernel(
    const float* __restrict__ X, int CP, const float* __restrict__ Wcat,
    const float* __restrict__ g, const float* __restrict__ bias,
    int D, int TWOD, float* __restrict__ PQ)
{
    __shared__ __align__(16) float As[64][36];
    __shared__ __align__(16) float Bs[32][68];
    const int bi = blockIdx.x * 64;
    const int bn = blockIdx.y * 64;
    const int t  = threadIdx.x;
    const int tx = t & 15, ty = t >> 4;
    const int CP4 = CP / 4;
    const float4* xp = (const float4*)X;

    float acc[4][4] = {};
    float4 pa[2], pb[2];

    int c0 = 0;
    int KC4 = ((CP < 32) ? CP : 32) >> 2;
    #pragma unroll
    for (int s = 0; s < 2; ++s){
        int f = t + 256*s;
        if (f < 64*KC4){
            int r = f / KC4, c4 = f - r*KC4;
            pa[s] = xp[(long)(bi + r)*CP4 + c4];
        }
        if (f < 64*KC4){
            int r = f >> 4, c4 = f & 15;
            pb[s] = *(const float4*)&Wcat[(long)r * TWOD + bn + c4*4];
        }
    }

    for (;;){
        __syncthreads();
        #pragma unroll
        for (int s = 0; s < 2; ++s){
            int f = t + 256*s;
            if (f < 64*KC4){
                int r = f / KC4, c4 = f - r*KC4;
                *(float4*)&As[r][c4*4] = pa[s];
            }
            if (f < 64*KC4){
                int r = f >> 4, c4 = f & 15;
                *(float4*)&Bs[r][c4*4] = pb[s];
            }
        }
        __syncthreads();
        const int KC  = KC4 * 4;
        const int c0n = c0 + 32;
        int KC4n = 0;
        if (c0n < CP){
            KC4n = (((CP - c0n) < 32) ? (CP - c0n) : 32) >> 2;
            #pragma unroll
            for (int s = 0; s < 2; ++s){
                int f = t + 256*s;
                if (f < 64*KC4n){
                    int r = f / KC4n, c4 = f - r*KC4n;
                    pa[s] = xp[(long)(bi + r)*CP4 + (c0n >> 2) + c4];
                }
                if (f < 64*KC4n){
                    int r = f >> 4, c4 = f & 15;
                    pb[s] = *(const float4*)&Wcat[(long)(c0n + r) * TWOD + bn + c4*4];
                }
            }
        }
        for (int c = 0; c < KC; c += 4){
            float4 A[4];
            #pragma unroll
            for (int ii = 0; ii < 4; ++ii) A[ii] = *(const float4*)&As[ty + 16*ii][c];
            float B0[4], B1[4], B2[4], B3[4];
            #pragma unroll
            for (int jj = 0; jj < 4; ++jj){
                B0[jj] = Bs[c+0][tx + 16*jj];
                B1[jj] = Bs[c+1][tx + 16*jj];
                B2[jj] = Bs[c+2][tx + 16*jj];
                B3[jj] = Bs[c+3][tx + 16*jj];
            }
            #pragma unroll
            for (int ii = 0; ii < 4; ++ii)
                #pragma unroll
                for (int jj = 0; jj < 4; ++jj){
                    acc[ii][jj] = fmaf(A[ii].x, B0[jj], acc[ii][jj]);
                    acc[ii][jj] = fmaf(A[ii].y, B1[jj], acc[ii][jj]);
                    acc[ii][jj] = fmaf(A[ii].z, B2[jj], acc[ii][jj]);
                    acc[ii][jj] = fmaf(A[ii].w, B3[jj], acc[ii][jj]);
                }
        }
        if (c0n >= CP) break;
        c0 = c0n; KC4 = KC4n;
    }

    #pragma unroll
    for (int jj = 0; jj < 4; ++jj){
        int n = bn + tx + 16*jj;
        int d = (n < D) ? n : n - D;
        float gg = g[d] * BN_INV;
        float bb = (n < D) ? 0.f : bias[d];
        #pragma unroll
        for (int ii = 0; ii < 4; ++ii)
            PQ[(long)(bi + ty + 16*ii) * TWOD + n] = fmaf(acc[ii][jj], gg, bb);
    }
}

template<int D, int RPB>
__global__ __launch_bounds__(256) void gather_max_kernel(
    const float* __restrict__ PQ, const int* __restrict__ idx, int N,
    float* __restrict__ y, float* __restrict__ sqout)
{
    __shared__ int   lidx[RPB][KNN];
    __shared__ float sred[4];
    const int rb = blockIdx.x * RPB;
    const int t  = threadIdx.x;
    if (t < RPB * KNN) lidx[t / KNN][t % KNN] = idx[(long)rb * KNN + t];
    __syncthreads();

    const int r = t / D, d = t - r * D;
    const int row = rb + r;
    const long base = (long)(row / N) * N;
    const int TWOD = 2 * D;

    float q = PQ[(long)row * TWOD + D + d];
    float m = -INFINITY;
    #pragma unroll
    for (int k = 0; k < KNN; ++k){
        int j = lidx[r][k];
        m = fmaxf(m, PQ[(base + j) * TWOD + d]);
    }
    float val = leaky(m + q);
    y[(long)row * D + d] = val;

    float ss = val * val;
    #pragma unroll
    for (int off = 32; off; off >>= 1) ss += __shfl_xor(ss, off);
    if ((t & 63) == 0) sred[t >> 6] = ss;
    __syncthreads();
    if (d == 0){
        constexpr int WPR = D / 64;
        float s = 0.f;
        int w0 = (r * D) >> 6;
        #pragma unroll
        for (int w = 0; w < WPR; ++w) s += sred[w0 + w];
        sqout[row] = s;
    }
}

// ---------------- head as tiled GEMMs ----------------

__global__ __launch_bounds__(256) void head_gemm1_kernel(
    const float* __restrict__ x1, const float* __restrict__ x2,
    const float* __restrict__ x3, const float* __restrict__ x4,
    const float* __restrict__ Wc5, const float* __restrict__ g5,
    const float* __restrict__ b5, float* __restrict__ gf, int R)
{
    __shared__ __align__(16) float As[64][68];
    __shared__ __align__(16) float Bs[64][68];
    const int bi = blockIdx.x * 64;
    const int bn = blockIdx.y * 64;
    const int t  = threadIdx.x;
    const int tx = t & 15, ty = t >> 4;

    float acc[4][4] = {};

    #pragma unroll 1
    for (int kc = 0; kc < 8; ++kc){
        const float* src; int ld, coff;
        if      (kc == 0){ src = x1; ld = 64;  coff = 0; }
        else if (kc == 1){ src = x2; ld = 64;  coff = 0; }
        else if (kc <  4){ src = x3; ld = 128; coff = (kc-2)*64; }
        else             { src = x4; ld = 256; coff = (kc-4)*64; }
        __syncthreads();
        for (int f = t; f < 64*16; f += 256){
            int r = f >> 4, c4 = f & 15;
            *(float4*)&As[r][c4*4] = *(const float4*)&src[(long)(bi + r)*ld + coff + c4*4];
            *(float4*)&Bs[r][c4*4] = *(const float4*)&Wc5[(long)(kc*64 + r)*128 + bn + c4*4];
        }
        __syncthreads();
        for (int c = 0; c < 64; c += 4){
            float4 A[4];
            #pragma unroll
            for (int ii = 0; ii < 4; ++ii) A[ii] = *(const float4*)&As[ty + 16*ii][c];
            float B0[4], B1[4], B2[4], B3[4];
            #pragma unroll
            for (int jj = 0; jj < 4; ++jj){
                B0[jj] = Bs[c+0][tx + 16*jj];
                B1[jj] = Bs[c+1][tx + 16*jj];
                B2[jj] = Bs[c+2][tx + 16*jj];
                B3[jj] = Bs[c+3][tx + 16*jj];
            }
            #pragma unroll
            for (int ii = 0; ii < 4; ++ii)
                #pragma unroll
                for (int jj = 0; jj < 4; ++jj){
                    acc[ii][jj] = fmaf(A[ii].x, B0[jj], acc[ii][jj]);
                    acc[ii][jj] = fmaf(A[ii].y, B1[jj], acc[ii][jj]);
                    acc[ii][jj] = fmaf(A[ii].z, B2[jj], acc[ii][jj]);
                    acc[ii][jj] = fmaf(A[ii].w, B3[jj], acc[ii][jj]);
                }
        }
    }

    #pragma unroll
    for (int jj = 0; jj < 4; ++jj){
        int n = bn + tx + 16*jj;
        float gg = g5[n] * BN_INV, bb = b5[n];
        #pragma unroll
        for (int ii = 0; ii < 4; ++ii)
            gf[(long)(bi + ty + 16*ii)*128 + n] = leaky(fmaf(acc[ii][jj], gg, bb));
    }
}

__global__ __launch_bounds__(256) void head_lngemm_kernel(
    const float* __restrict__ hin, const float* __restrict__ W,
    const float* __restrict__ bo, const float* __restrict__ lg,
    const float* __restrict__ lb, float* __restrict__ hout, int R)
{
    __shared__ __align__(16) float As[64][68];
    __shared__ __align__(16) float Bs[64][132];
    const int bi = blockIdx.x * 64;
    const int t  = threadIdx.x;
    const int tx = t & 15, ty = t >> 4;

    float acc[4][8] = {};

    #pragma unroll 1
    for (int kc = 0; kc < 2; ++kc){
        __syncthreads();
        for (int f = t; f < 64*16; f += 256){
            int r = f >> 4, c4 = f & 15;
            *(float4*)&As[r][c4*4] = *(const float4*)&hin[(long)(bi + r)*128 + kc*64 + c4*4];
        }
        for (int f = t; f < 64*32; f += 256){
            int r = f >> 5, c4 = f & 31;
            *(float4*)&Bs[r][c4*4] = *(const float4*)&W[(long)(kc*64 + r)*128 + c4*4];
        }
        __syncthreads();
        for (int c = 0; c < 64; c += 4){
            float4 A[4];
            #pragma unroll
            for (int ii = 0; ii < 4; ++ii) A[ii] = *(const float4*)&As[ty + 16*ii][c];
            float B0[8], B1[8], B2[8], B3[8];
            #pragma unroll
            for (int jj = 0; jj < 8; ++jj){
                B0[jj] = Bs[c+0][tx + 16*jj];
                B1[jj] = Bs[c+1][tx + 16*jj];
                B2[jj] = Bs[c+2][tx + 16*jj];
                B3[jj] = Bs[c+3][tx + 16*jj];
            }
            #pragma unroll
            for (int ii = 0; ii < 4; ++ii)
                #pragma unroll
                for (int jj = 0; jj < 8; ++jj){
                    acc[ii][jj] = fmaf(A[ii].x, B0[jj], acc[ii][jj]);
                    acc[ii][jj] = fmaf(A[ii].y, B1[jj], acc[ii][jj]);
                    acc[ii][jj] = fmaf(A[ii].z, B2[jj], acc[ii][jj]);
                    acc[ii][jj] = fmaf(A[ii].w, B3[jj], acc[ii][jj]);
                }
        }
    }

    float bon[8], lgn[8], lbn[8];
    #pragma unroll
    for (int jj = 0; jj < 8; ++jj){
        int n = tx + 16*jj;
        bon[jj] = bo[n]; lgn[jj] = lg[n]; lbn[jj] = lb[n];
    }
    #pragma unroll
    for (int ii = 0; ii < 4; ++ii){
        float s1 = 0.f, s2 = 0.f;
        #pragma unroll
        for (int jj = 0; jj < 8; ++jj){
            float a = acc[ii][jj] + bon[jj];
            acc[ii][jj] = a;
            s1 += a; s2 += a*a;
        }
        #pragma unroll
        for (int off = 8; off; off >>= 1){
            s1 += __shfl_xor(s1, off);
            s2 += __shfl_xor(s2, off);
        }
        float m = s1 * (1.f/128.f);
        float v = s2 * (1.f/128.f) - m*m;
        float rinv = rsqrtf(v + 1e-5f);
        long r = bi + ty + 16*ii;
        #pragma unroll
        for (int jj = 0; jj < 8; ++jj)
            hout[r*128 + tx + 16*jj] = leaky((acc[ii][jj] - m) * rinv * lgn[jj] + lbn[jj]);
    }
}

#define OP 16
__global__ __launch_bounds__(256) void head_out_kernel(
    const float* __restrict__ h, const float* __restrict__ feats,
    const float* __restrict__ Wo3, const float* __restrict__ bo3,
    float* __restrict__ out, int R)
{
    __shared__ __align__(16) float hs[OP][132];
    __shared__ float f14[OP][14];
    const int t  = threadIdx.x;
    const long p0 = (long)blockIdx.x * OP;

    for (int f = t; f < OP*32; f += 256){
        int r = f >> 5, c4 = f & 31;
        *(float4*)&hs[r][c4*4] = *(const float4*)&h[(p0 + r)*128 + c4*4];
    }
    if (t < OP*14) f14[t/14][t%14] = feats[(p0 + t/14)*116 + t%14];
    __syncthreads();

    const int w = t >> 6, l = t & 63;
    if (l < 38){
        float o[4];
        float bt = bo3[l];
        #pragma unroll
        for (int pp = 0; pp < 4; ++pp) o[pp] = bt;
        for (int c = 0; c < 128; ++c){
            float wv = Wo3[c*38 + l];
            #pragma unroll
            for (int pp = 0; pp < 4; ++pp)
                o[pp] = fmaf(hs[w*4 + pp][c], wv, o[pp]);
        }
        #pragma unroll
        for (int pp = 0; pp < 4; ++pp){
            int p = w*4 + pp;
            float val = o[pp] + ((l < 14) ? f14[p][l] : 0.f);
            out[(p0 + p)*38 + l] = val;
        }
    }
}

// ---------------- fallback kNN + EdgeConv + head (known-good, N != 4096) ----------------
__global__ __launch_bounds__(256) void knn_kernel(
    const float* __restrict__ x, int N, int CP4, int* __restrict__ idx_out)
{
    __shared__ float4 xi4[32];
    __shared__ float drow[4096];
    __shared__ float rv[4];
    __shared__ int   ri[4];

    int row = blockIdx.x;
    int b = row / N;
    int t = threadIdx.x;
    const float4* xp = (const float4*)x;

    if (t < CP4) xi4[t] = xp[(long)row * CP4 + t];
    __syncthreads();

    long bb = (long)b * N * CP4;
    for (int j = t; j < N; j += 256){
        const float4* p = xp + bb + (long)j * CP4;
        float acc = 0.f;
        #pragma unroll 4
        for (int c = 0; c < CP4; ++c){
            float4 xv = p[c], yv = xi4[c];
            float dx = xv.x - yv.x, dy = xv.y - yv.y;
            float dz = xv.z - yv.z, dw = xv.w - yv.w;
            acc += dx*dx + dy*dy + dz*dz + dw*dw;
        }
        drow[j] = -acc;
    }
    __syncthreads();

    for (int it = 0; it < KNN; ++it){
        float bv = -INFINITY; int bi = N;
        for (int j = t; j < N; j += 256){
            float v = drow[j];
            if (v > bv){ bv = v; bi = j; }
        }
        #pragma unroll
        for (int off = 32; off > 0; off >>= 1){
            float ov = __shfl_xor(bv, off);
            int   oi = __shfl_xor(bi, off);
            if (ov > bv || (ov == bv && oi < bi)){ bv = ov; bi = oi; }
        }
        if ((t & 63) == 0){ rv[t >> 6] = bv; ri[t >> 6] = bi; }
        __syncthreads();
        if (t == 0){
            float fv = rv[0]; int fi = ri[0];
            #pragma unroll
            for (int w = 1; w < 4; ++w){
                if (rv[w] > fv || (rv[w] == fv && ri[w] < fi)){ fv = rv[w]; fi = ri[w]; }
            }
            idx_out[(long)row * KNN + it] = fi;
            drow[fi] = -INFINITY;
        }
        __syncthreads();
    }
}

template<int D, int KPT>
__global__ __launch_bounds__(256) void edge_conv_kernel(
    const float* __restrict__ x, int N, int C, int CP,
    const float* __restrict__ W, const float* __restrict__ g,
    const float* __restrict__ bias, const int* __restrict__ idx,
    float* __restrict__ y, float* __restrict__ sqout)
{
    __shared__ float xi[128];
    __shared__ float nbr[KNN * 128];
    __shared__ float t2[D];
    __shared__ unsigned um[D];
    __shared__ float sred[4];

    int row = blockIdx.x;
    int b = row / N;
    int t = threadIdx.x;

    for (int c = t; c < C; c += 256) xi[c] = x[(long)row * CP + c];
    for (int kk = 0; kk < KNN; ++kk){
        int j = idx[(long)row * KNN + kk];
        long nb = ((long)b * N + j) * CP;
        for (int c = t; c < C; c += 256) nbr[kk * C + c] = x[nb + c];
    }
    __syncthreads();

    for (int d = t; d < D; d += 256){
        float s = 0.f;
        for (int c = 0; c < C; ++c) s += xi[c] * W[(C + c) * D + d];
        t2[d] = s; um[d] = 0u;
    }
    __syncthreads();

    const int d  = t % D;
    const int kg = t / D;
    float s[KPT];
    #pragma unroll
    for (int q = 0; q < KPT; ++q) s[q] = t2[d];

    const float* nb0 = &nbr[(kg * KPT) * C];
    for (int c = 0; c < C; ++c){
        float w   = W[c * D + d];
        float xic = xi[c];
        #pragma unroll
        for (int q = 0; q < KPT; ++q)
            s[q] += (nb0[q * C + c] - xic) * w;
    }
    float g_ = g[d] * BN_INV, b_ = bias[d];
    float m = -INFINITY;
    #pragma unroll
    for (int q = 0; q < KPT; ++q)
        m = fmaxf(m, leaky(s[q] * g_ + b_));
    atomicMax(&um[d], f2o(m));
    __syncthreads();

    float ss = 0.f;
    for (int dd = t; dd < D; dd += 256){
        float val = o2f(um[dd]);
        y[(long)row * D + dd] = val;
        ss += val * val;
    }
    #pragma unroll
    for (int off = 32; off; off >>= 1) ss += __shfl_xor(ss, off);
    if ((t & 63) == 0) sred[t >> 6] = ss;
    __syncthreads();
    if (t == 0) sqout[row] = sred[0] + sred[1] + sred[2] + sred[3];
}

#define HP 8
__global__ __launch_bounds__(128) void head_kernel(
    const float* __restrict__ x1, const float* __restrict__ x2,
    const float* __restrict__ x3, const float* __restrict__ x4,
    const float* __restrict__ feats,
    const float* __restrict__ Wc5, const float* __restrict__ g5, const float* __restrict__ b5,
    const float* __restrict__ Wo1, const float* __restrict__ bo1,
    const float* __restrict__ lg1, const float* __restrict__ lb1,
    const float* __restrict__ Wo2, const float* __restrict__ bo2,
    const float* __restrict__ lg2, const float* __restrict__ lb2,
    const float* __restrict__ Wo3, const float* __restrict__ bo3,
    float* __restrict__ out, int N, int R)
{
    __shared__ __align__(16) float cat[HP][520];
    __shared__ __align__(16) float hb[HP][132];
    __shared__ float wsum[2][HP], wsq[2][HP];
    __shared__ float f14[HP][14];

    const int t = threadIdx.x;
    const long p0 = (long)blockIdx.x * HP;
    const int wid = t >> 6;

    long rows[HP];
    #pragma unroll
    for (int p = 0; p < HP; ++p){
        long row = p0 + p; if (row >= R) row = R - 1;
        rows[p] = row;
        cat[p][t]       = (t < 64) ? x1[row*64 + t] : x2[row*64 + (t-64)];
        cat[p][128 + t] = x3[row*128 + t];
        cat[p][256 + t] = x4[row*256 + t];
        cat[p][384 + t] = x4[row*256 + 128 + t];
        if (t < 14) f14[p][t] = feats[row*116 + t];
    }
    __syncthreads();

    const float g5t = g5[t] * BN_INV, b5t = b5[t];
    float acc[HP];
    #pragma unroll
    for (int p = 0; p < HP; ++p) acc[p] = 0.f;
    for (int c4 = 0; c4 < 128; ++c4){
        float w0 = Wc5[(4*c4+0)*128 + t];
        float w1 = Wc5[(4*c4+1)*128 + t];
        float w2 = Wc5[(4*c4+2)*128 + t];
        float w3 = Wc5[(4*c4+3)*128 + t];
        #pragma unroll
        for (int p = 0; p < HP; ++p){
            float4 cv = *(const float4*)&cat[p][4*c4];
            acc[p] = fmaf(cv.x, w0, acc[p]);
            acc[p] = fmaf(cv.y, w1, acc[p]);
            acc[p] = fmaf(cv.z, w2, acc[p]);
            acc[p] = fmaf(cv.w, w3, acc[p]);
        }
    }
    #pragma unroll
    for (int p = 0; p < HP; ++p) hb[p][t] = leaky(fmaf(acc[p], g5t, b5t));
    __syncthreads();

    for (int layer = 0; layer < 2; ++layer){
        const float* W  = layer ? Wo2 : Wo1;
        const float* bo = layer ? bo2 : bo1;
        const float* lg = layer ? lg2 : lg1;
        const float* lb = layer ? lb2 : lb1;
        float a2[HP];
        float bot = bo[t];
        #pragma unroll
        for (int p = 0; p < HP; ++p) a2[p] = bot;
        for (int c4 = 0; c4 < 32; ++c4){
            float w0 = W[(4*c4+0)*128 + t];
            float w1 = W[(4*c4+1)*128 + t];
            float w2 = W[(4*c4+2)*128 + t];
            float w3 = W[(4*c4+3)*128 + t];
            #pragma unroll
            for (int p = 0; p < HP; ++p){
                float4 hv = *(const float4*)&hb[p][4*c4];
                a2[p] = fmaf(hv.x, w0, a2[p]);
                a2[p] = fmaf(hv.y, w1, a2[p]);
                a2[p] = fmaf(hv.z, w2, a2[p]);
                a2[p] = fmaf(hv.w, w3, a2[p]);
            }
        }
        #pragma unroll
        for (int p = 0; p < HP; ++p){
            float s1 = a2[p], s2 = a2[p]*a2[p];
            #pragma unroll
            for (int off = 32; off; off >>= 1){
                s1 += __shfl_xor(s1, off);
                s2 += __shfl_xor(s2, off);
            }
            if ((t & 63) == 0){ wsum[wid][p] = s1; wsq[wid][p] = s2; }
        }
        __syncthreads();
        float lgt = lg[t], lbt = lb[t];
        float hn[HP];
        #pragma unroll
        for (int p = 0; p < HP; ++p){
            float m  = (wsum[0][p] + wsum[1][p]) * (1.f/128.f);
            float v  = (wsq[0][p]  + wsq[1][p])  * (1.f/128.f) - m*m;
            float dm = a2[p] - m;
            hn[p] = leaky(dm * rsqrtf(v + 1e-5f) * lgt + lbt);
        }
        __syncthreads();
        #pragma unroll
        for (int p = 0; p < HP; ++p) hb[p][t] = hn[p];
        __syncthreads();
    }

    if (t < 38){
        float o[HP];
        float bt = bo3[t];
        #pragma unroll
        for (int p = 0; p < HP; ++p) o[p] = bt;
        for (int c = 0; c < 128; ++c){
            float w = Wo3[c*38 + t];
            #pragma unroll
            for (int p = 0; p < HP; ++p) o[p] = fmaf(hb[p][c], w, o[p]);
        }
        #pragma unroll
        for (int p = 0; p < HP; ++p){
            float val = o[p] + ((t < 14) ? f14[p][t] : 0.f);
            out[rows[p]*38 + t] = val;
        }
    }
}

extern "C" void kernel_launch(void* const* d_in, const int* in_sizes, int n_in,
                              void* d_out, int out_size, void* d_ws, size_t ws_size,
                              hipStream_t stream)
{
    const float* xyz  = (const float*)d_in[0];
    const float* scal = (const float*)d_in[1];
    const float* rot  = (const float*)d_in[2];
    const float* opac = (const float*)d_in[3];
    const float* colr = (const float*)d_in[4];
    const float* pose = (const float*)d_in[5];
    const float* lbs  = (const float*)d_in[6];
    const float* Wc1 = (const float*)d_in[7];  const float* g1 = (const float*)d_in[8];  const float* b1 = (const float*)d_in[9];
    const float* Wc2 = (const float*)d_in[10]; const float* g2 = (const float*)d_in[11]; const float* b2 = (const float*)d_in[12];
    const float* Wc3 = (const float*)d_in[13]; const float* g3 = (const float*)d_in[14]; const float* b3 = (const float*)d_in[15];
    const float* Wc4 = (const float*)d_in[16]; const float* g4 = (const float*)d_in[17]; const float* b4 = (const float*)d_in[18];
    const float* Wc5 = (const float*)d_in[19]; const float* g5 = (const float*)d_in[20]; const float* b5 = (const float*)d_in[21];
    const float* Wo1 = (const float*)d_in[22]; const float* bo1 = (const float*)d_in[23];
    const float* lg1 = (const float*)d_in[24]; const float* lb1 = (const float*)d_in[25];
    const float* Wo2 = (const float*)d_in[26]; const float* bo2 = (const float*)d_in[27];
    const float* lg2 = (const float*)d_in[28]; const float* lb2 = (const float*)d_in[29];
    const float* Wo3 = (const float*)d_in[30]; const float* bo3 = (const float*)d_in[31];

    const int N = in_sizes[0] / 3;      // 4096
    const int B = in_sizes[5] / 75;     // 2
    const int R = B * N;

    char* ws = (char*)d_ws;
    size_t o = 0;
    float* feats = (float*)(ws + o); o += (size_t)R * 116 * 4;
    float* x1    = (float*)(ws + o); o += (size_t)R * 64  * 4;
    float* x2    = (float*)(ws + o); o += (size_t)R * 64  * 4;
    float* x3    = (float*)(ws + o); o += (size_t)R * 128 * 4;
    float* x4    = (float*)(ws + o); o += (size_t)R * 256 * 4;
    int*   idx   = (int*)  (ws + o); o += (size_t)R * KNN * 4;
    float* sq    = (float*)(ws + o); o += (size_t)R * 4;
    float* Wcat  = (float*)(ws + o); o += (size_t)104960 * 4;
    float* G     = (float*)(ws + o);
    float* PQ    = G;                   // alias: stream-ordered reuse
    float* gf    = G;                   // head temps alias G (free after last gather)
    float* h1    = G + (size_t)R * 128;
    float* h2    = G + (size_t)R * 256;
    size_t need  = o + (size_t)B * N * N * 4;

    const bool fast = (N == 4096) && (ws_size >= need);

    build_feats_kernel<<<R, 128, 0, stream>>>(xyz, scal, rot, opac, colr, pose, lbs, feats, sq, N);

    if (fast){
        const int NT = 32;                       // 4096/128 tiles
        dim3 gg(NT*(NT+1)/2, 1, B);              // packed upper triangle
        float* Wcat1 = Wcat;
        float* Wcat2 = Wcat + 14848;
        float* Wcat3 = Wcat + 23040;
        float* Wcat4 = Wcat + 39424;

        prep_all_wcat_kernel<<<(104960 + 255)/256, 256, 0, stream>>>(Wc1, Wc2, Wc3, Wc4, Wcat);

        // L1: C=113 (CP=116), D=64
        dist_gemm_kernel<116><<<gg, 256, 0, stream>>>(feats, N, 116, G);
        topk_kernel<<<R, 256, 0, stream>>>(G, sq, N, idx);
        gemm_pq64_kernel<<<dim3(R/64, 2), 256, 0, stream>>>(feats, 116, Wcat1, g1, b1, 64, 128, PQ);
        gather_max_kernel<64, 4><<<R/4, 256, 0, stream>>>(PQ, idx, N, x1, sq);

        // L2: C=64, D=64
        dist_gemm_kernel<64><<<gg, 256, 0, stream>>>(x1, N, 64, G);
        topk_kernel<<<R, 256, 0, stream>>>(G, sq, N, idx);
        gemm_pq64_kernel<<<dim3(R/64, 2), 256, 0, stream>>>(x1, 64, Wcat2, g2, b2, 64, 128, PQ);
        gather_max_kernel<64, 4><<<R/4, 256, 0, stream>>>(PQ, idx, N, x2, sq);

        // L3: C=64, D=128
        dist_gemm_kernel<64><<<gg, 256, 0, stream>>>(x2, N, 64, G);
        topk_kernel<<<R, 256, 0, stream>>>(G, sq, N, idx);
        gemm_pq64_kernel<<<dim3(R/64, 4), 256, 0, stream>>>(x2, 64, Wcat3, g3, b3, 128, 256, PQ);
        gather_max_kernel<128, 2><<<R/2, 256, 0, stream>>>(PQ, idx, N, x3, sq);

        // L4: C=128, D=256
        dist_gemm_kernel<128><<<gg, 256, 0, stream>>>(x3, N, 128, G);
        topk_kernel<<<R, 256, 0, stream>>>(G, sq, N, idx);
        gemm_pq_kernel<<<dim3(R/128, 4), 256, 0, stream>>>(x3, 128, Wcat4, g4, b4, 256, 512, PQ);
        gather_max_kernel<256, 1><<<R, 256, 0, stream>>>(PQ, idx, N, x4, sq);

        // head: tiled GEMMs (gf/h1/h2 alias G, free after last gather)
        head_gemm1_kernel<<<dim3(R/64, 2), 256, 0, stream>>>(x1, x2, x3, x4, Wc5, g5, b5, gf, R);
        head_lngemm_kernel<<<R/64, 256, 0, stream>>>(gf, Wo1, bo1, lg1, lb1, h1, R);
        head_lngemm_kernel<<<R/64, 256, 0, stream>>>(h1, Wo2, bo2, lg2, lb2, h2, R);
        head_out_kernel<<<R/OP, 256, 0, stream>>>(h2, feats, Wo3, bo3, (float*)d_out, R);
    } else {
        knn_kernel<<<R, 256, 0, stream>>>(feats, N, 116/4, idx);
        edge_conv_kernel<64, 5><<<R, 256, 0, stream>>>(feats, N, 113, 116, Wc1, g1, b1, idx, x1, sq);
        knn_kernel<<<R, 256, 0, stream>>>(x1, N, 64/4, idx);
        edge_conv_kernel<64, 5><<<R, 256, 0, stream>>>(x1, N, 64, 64, Wc2, g2, b2, idx, x2, sq);
        knn_kernel<<<R, 256, 0, stream>>>(x2, N, 64/4, idx);
        edge_conv_kernel<128, 10><<<R, 256, 0, stream>>>(x2, N, 64, 64, Wc3, g3, b3, idx, x3, sq);
        knn_kernel<<<R, 256, 0, stream>>>(x3, N, 128/4, idx);
        edge_conv_kernel<256, 20><<<R, 256, 0, stream>>>(x3, N, 128, 128, Wc4, g4, b4, idx, x4, sq);

        head_kernel<<<(R + HP - 1)/HP, 128, 0, stream>>>(x1, x2, x3, x4, feats,
                                           Wc5, g5, b5, Wo1, bo1, lg1, lb1,
                                           Wo2, bo2, lg2, lb2, Wo3, bo3,
                                           (float*)d_out, N, R);
    }
}

// Round 11
// 810.615 us; speedup vs baseline: 1.1123x; 1.1123x over previous
//
#include <hip/hip_runtime.h>
#include <math.h>

#define KNN 20
// 1/sqrt(1 + 1e-5)
#define BN_INV 0.9999950000374997f

__device__ __forceinline__ unsigned f2o(float f){
    unsigned u = __float_as_uint(f);
    return (u >> 31) ? ~u : (u | 0x80000000u);
}
__device__ __forceinline__ float o2f(unsigned u){
    return __uint_as_float((u >> 31) ? (u & 0x7fffffffu) : ~u);
}
__device__ __forceinline__ float leaky(float v){ return v > 0.f ? v : 0.2f * v; }

// Build feats[B,N,116] = [gfeat(14) | lbs(24) | pose(75) | pad0(3)]; also sq[row]
__global__ __launch_bounds__(128) void build_feats_kernel(
    const float* __restrict__ xyz, const float* __restrict__ scale,
    const float* __restrict__ rot, const float* __restrict__ opac,
    const float* __restrict__ color, const float* __restrict__ pose,
    const float* __restrict__ lbs, float* __restrict__ feats,
    float* __restrict__ sqout, int N)
{
    __shared__ float sred[2];
    int row = blockIdx.x;           // b*N + n
    int b = row / N, n = row % N;
    int c = threadIdx.x;            // 128 threads, write c<116
    float v = 0.f;
    if      (c <   3) v = xyz  [n*3 + c];
    else if (c <   6) v = scale[n*3 + c-3];
    else if (c <  10) v = rot  [n*4 + c-6];
    else if (c <  11) v = opac [n];
    else if (c <  14) v = color[n*3 + c-11];
    else if (c <  38) v = lbs  [n*24 + c-14];
    else if (c < 113) v = pose [b*75 + c-38];
    if (c < 116) feats[(long)row*116 + c] = v;
    float ss = v * v;
    #pragma unroll
    for (int off = 32; off; off >>= 1) ss += __shfl_xor(ss, off);
    if ((c & 63) == 0) sred[c >> 6] = ss;
    __syncthreads();
    if (c == 0) sqout[row] = sred[0] + sred[1];
}

// ---------------- kNN: packed-symmetric Gram + threshold-select top-k ----------------

// Packed upper-triangle grid; KC=32 chunks -> 36 KB LDS -> 4 blocks/CU.
// (Round-9 measured-good version: NO register prefetch, NO min-waves bound —
//  the round-10 prefetch + launch_bounds(256,4) combo spilled acc to scratch:
//  FETCH 23->100 MB, WRITE 131->286 MB, dur 79->105 us.)
// Accumulation order (ascending c) bit-identical across rounds.
template<int C>
__global__ __launch_bounds__(256) void dist_gemm_kernel(
    const float* __restrict__ x, int N, int CP, float* __restrict__ G)
{
    __shared__ __align__(16) float smem[9216];       // 36864 B
    float (*xi)[36] = (float(*)[36])smem;            // [128][36]
    float (*xj)[36] = (float(*)[36])(smem + 128*36);

    const int q = blockIdx.x;
    int bjt = (int)((sqrtf(8.f*(float)q + 1.f) - 1.f) * 0.5f);
    while ((bjt+1)*(bjt+2)/2 <= q) ++bjt;
    while (bjt*(bjt+1)/2 > q) --bjt;
    const int bit = q - bjt*(bjt+1)/2;               // bi-tile <= bj-tile
    const int bi = bit * 128;
    const int bj = bjt * 128;

    const int b  = blockIdx.z;
    const int t  = threadIdx.x;
    const int tx = t & 15, ty = t >> 4;
    const int CP4 = CP / 4;
    const long base = (long)b * N;
    const float4* xp = (const float4*)x;

    float acc[8][8] = {};

    for (int c0 = 0; c0 < C; c0 += 32){
        const int KC  = (C - c0 < 32) ? (C - c0) : 32;
        const int KC4 = KC >> 2;
        __syncthreads();
        if (KC4 == 8){
            for (int f = t; f < 128 * 8; f += 256){
                int r = f >> 3, c4 = f & 7;
                *(float4*)&xi[r][c4 * 4] = xp[(base + bi + r) * CP4 + (c0 >> 2) + c4];
                *(float4*)&xj[r][c4 * 4] = xp[(base + bj + r) * CP4 + (c0 >> 2) + c4];
            }
        } else {
            for (int f = t; f < 128 * KC4; f += 256){
                int r = f / KC4, c4 = f - r * KC4;
                *(float4*)&xi[r][c4 * 4] = xp[(base + bi + r) * CP4 + (c0 >> 2) + c4];
                *(float4*)&xj[r][c4 * 4] = xp[(base + bj + r) * CP4 + (c0 >> 2) + c4];
            }
        }
        __syncthreads();
        for (int c = 0; c < KC; c += 4){
            float4 A[8], Bv[8];
            #pragma unroll
            for (int ii = 0; ii < 8; ++ii) A[ii]  = *(const float4*)&xi[ty + 16*ii][c];
            #pragma unroll
            for (int jj = 0; jj < 8; ++jj) Bv[jj] = *(const float4*)&xj[tx + 16*jj][c];
            #pragma unroll
            for (int ii = 0; ii < 8; ++ii)
                #pragma unroll
                for (int jj = 0; jj < 8; ++jj){
                    acc[ii][jj] = fmaf(A[ii].x, Bv[jj].x, acc[ii][jj]);
                    acc[ii][jj] = fmaf(A[ii].y, Bv[jj].y, acc[ii][jj]);
                    acc[ii][jj] = fmaf(A[ii].z, Bv[jj].z, acc[ii][jj]);
                    acc[ii][jj] = fmaf(A[ii].w, Bv[jj].w, acc[ii][jj]);
                }
        }
    }

    // upper tile (coalesced)
    #pragma unroll
    for (int ii = 0; ii < 8; ++ii){
        long rbase = (base + bi + ty + 16*ii) * N + bj;
        #pragma unroll
        for (int jj = 0; jj < 8; ++jj)
            G[rbase + tx + 16*jj] = acc[ii][jj];
    }

    // mirror tile via two 64-row transpose half-passes (values bit-identical)
    if (bi != bj){
        float (*tr)[132] = (float(*)[132])smem;      // 64*132*4 = 33792 B
        #pragma unroll
        for (int h = 0; h < 2; ++h){
            __syncthreads();
            #pragma unroll
            for (int ii = 0; ii < 8; ++ii)
                #pragma unroll
                for (int jj = 4*h; jj < 4*h + 4; ++jj)
                    tr[tx + 16*(jj - 4*h)][ty + 16*ii] = acc[ii][jj];
            __syncthreads();
            const int cc = (t & 31) * 4;
            const int r0 = t >> 5;
            #pragma unroll
            for (int f = 0; f < 8; ++f){
                int r = r0 + 8 * f;
                *(float4*)&G[(base + bj + 64*h + r) * N + bi + cc] = *(const float4*)&tr[r][cc];
            }
        }
    }
}

// Per-row top-20 SET by key u_j = f2o(2*G[i][j] - sq[j]); threshold select.
#define TCAP 256
__global__ __launch_bounds__(256) void topk_kernel(
    const float* __restrict__ G, const float* __restrict__ sq,
    int N, int* __restrict__ idx_out)
{
    __shared__ unsigned smax[256];
    __shared__ unsigned cand_u[TCAP];
    __shared__ int      cand_j[TCAP];
    __shared__ unsigned cand_cnt;
    __shared__ unsigned sTu;

    const int row = blockIdx.x;
    const int b   = row >> 12;
    const int t   = threadIdx.x;
    const float4* g4  = (const float4*)(G  + (long)row * 4096);
    const float4* sq4 = (const float4*)(sq + (long)b   * 4096);

    unsigned u[16];
    #pragma unroll
    for (int qq = 0; qq < 4; ++qq){
        int v4 = t + 256 * qq;
        float4 gg = g4[v4];
        float4 ss = sq4[v4];
        u[4*qq+0] = f2o(fmaf(2.f, gg.x, -ss.x));
        u[4*qq+1] = f2o(fmaf(2.f, gg.y, -ss.y));
        u[4*qq+2] = f2o(fmaf(2.f, gg.z, -ss.z));
        u[4*qq+3] = f2o(fmaf(2.f, gg.w, -ss.w));
    }

    unsigned mu = u[0];
    #pragma unroll
    for (int q = 1; q < 16; ++q) mu = u[q] > mu ? u[q] : mu;
    smax[t] = mu;
    if (t == 0) cand_cnt = 0;
    __syncthreads();

    int rank = 0;
    for (int k = 0; k < 256; ++k){
        unsigned ou = smax[k];
        rank += (ou > mu) || (ou == mu && k < t);
    }
    if (rank == KNN - 1) sTu = mu;
    __syncthreads();
    const unsigned Tu = sTu;

    #pragma unroll
    for (int qq = 0; qq < 4; ++qq)
        #pragma unroll
        for (int m = 0; m < 4; ++m){
            int q = 4*qq + m;
            if (u[q] >= Tu){
                unsigned p = atomicAdd(&cand_cnt, 1u);
                if (p < TCAP){ cand_u[p] = u[q]; cand_j[p] = 4*(t + 256*qq) + m; }
            }
        }
    __syncthreads();
    const int cc = (int)cand_cnt;

    if (cc <= TCAP){
        if (t < cc){
            unsigned cu = cand_u[t]; int cj = cand_j[t];
            int r = 0;
            for (int k = 0; k < cc; ++k){
                unsigned ou = cand_u[k];
                r += (ou > cu) || (ou == cu && cand_j[k] < cj);
            }
            if (r < KNN) idx_out[(long)row * KNN + r] = cj;
        }
    } else {
        __shared__ unsigned rv[4]; __shared__ int ri[4]; __shared__ int gj_;
        unsigned lv = 0u; int lj = 0x7fffffff;
        #pragma unroll
        for (int q = 0; q < 16; ++q)
            if (u[q] > lv){ lv = u[q]; lj = 4*(t + 256*(q>>2)) + (q&3); }
        for (int it = 0; it < KNN; ++it){
            unsigned bv = lv; int bj = lj;
            #pragma unroll
            for (int off = 32; off; off >>= 1){
                unsigned ov = __shfl_xor(bv, off);
                int      oj = __shfl_xor(bj, off);
                if (ov > bv || (ov == bv && oj < bj)){ bv = ov; bj = oj; }
            }
            if ((t & 63) == 0){ rv[t >> 6] = bv; ri[t >> 6] = bj; }
            __syncthreads();
            if (t == 0){
                unsigned fv = rv[0]; int fj = ri[0];
                #pragma unroll
                for (int w = 1; w < 4; ++w)
                    if (rv[w] > fv || (rv[w] == fv && ri[w] < fj)){ fv = rv[w]; fj = ri[w]; }
                gj_ = fj;
                idx_out[(long)row * KNN + it] = fj;
            }
            __syncthreads();
            int fj = gj_;
            if (fj >= 0 && ((fj >> 2) & 255) == t){
                u[((fj >> 10) << 2) | (fj & 3)] = 0u;
                lv = 0u; lj = 0x7fffffff;
                #pragma unroll
                for (int q = 0; q < 16; ++q)
                    if (u[q] > lv){ lv = u[q]; lj = 4*(t + 256*(q>>2)) + (q&3); }
            }
            __syncthreads();
        }
    }
}

// ---------------- EdgeConv as P/Q GEMM + gather-max ----------------

__device__ __forceinline__ void wcat_emit(const float* __restrict__ W, int C, int D,
                                          int i, float* __restrict__ dst)
{
    int TWOD = 2 * D;
    int c = i / TWOD, n = i - c * TWOD;
    float v = 0.f;
    if (c < C) v = (n < D) ? W[c*D + n] : (W[(C + c)*D + (n - D)] - W[c*D + (n - D)]);
    dst[i] = v;
}

__global__ void prep_all_wcat_kernel(
    const float* __restrict__ Wc1, const float* __restrict__ Wc2,
    const float* __restrict__ Wc3, const float* __restrict__ Wc4,
    float* __restrict__ Wcat)
{
    int i = blockIdx.x * 256 + threadIdx.x;
    if      (i <  14848) wcat_emit(Wc1, 113,  64, i,          Wcat);
    else if (i <  23040) wcat_emit(Wc2,  64,  64, i - 14848,  Wcat + 14848);
    else if (i <  39424) wcat_emit(Wc3,  64, 128, i - 23040,  Wcat + 23040);
    else if (i < 104960) wcat_emit(Wc4, 128, 256, i - 39424,  Wcat + 39424);
}

// PQ = X @ Wcat with BN/bias epilogue. 128x128 tiles, KC=32, register prefetch.
// Per-element fmaf chain (ascending c) identical to prior rounds.
__global__ __launch_bounds__(256) void gemm_pq_kernel(
    const float* __restrict__ X, int CP, const float* __restrict__ Wcat,
    const float* __restrict__ g, const float* __restrict__ bias,
    int D, int TWOD, float* __restrict__ PQ)
{
    __shared__ __align__(16) float As[128][36];
    __shared__ __align__(16) float Bs[32][132];
    const int bi = blockIdx.x * 128;
    const int bn = blockIdx.y * 128;
    const int t  = threadIdx.x;
    const int tx = t & 15, ty = t >> 4;
    const int CP4 = CP / 4;
    const float4* xp = (const float4*)X;

    float acc[8][8] = {};
    float4 pa[4], pb[4];

    int c0 = 0;
    int KC4 = ((CP < 32) ? CP : 32) >> 2;
    #pragma unroll
    for (int s = 0; s < 4; ++s){
        int f = t + 256*s;
        if (f < 128*KC4){
            int r = f / KC4, c4 = f - r*KC4;
            pa[s] = xp[(long)(bi + r)*CP4 + c4];
        }
        if (f < 128*KC4){
            int r = f >> 5, c4 = f & 31;
            pb[s] = *(const float4*)&Wcat[(long)r * TWOD + bn + c4*4];
        }
    }

    for (;;){
        __syncthreads();
        #pragma unroll
        for (int s = 0; s < 4; ++s){
            int f = t + 256*s;
            if (f < 128*KC4){
                int r = f / KC4, c4 = f - r*KC4;
                *(float4*)&As[r][c4*4] = pa[s];
            }
            if (f < 128*KC4){
                int r = f >> 5, c4 = f & 31;
                *(float4*)&Bs[r][c4*4] = pb[s];
            }
        }
        __syncthreads();
        const int KC  = KC4 * 4;
        const int c0n = c0 + 32;
        int KC4n = 0;
        if (c0n < CP){
            KC4n = (((CP - c0n) < 32) ? (CP - c0n) : 32) >> 2;
            #pragma unroll
            for (int s = 0; s < 4; ++s){
                int f = t + 256*s;
                if (f < 128*KC4n){
                    int r = f / KC4n, c4 = f - r*KC4n;
                    pa[s] = xp[(long)(bi + r)*CP4 + (c0n >> 2) + c4];
                }
                if (f < 128*KC4n){
                    int r = f >> 5, c4 = f & 31;
                    pb[s] = *(const float4*)&Wcat[(long)(c0n + r) * TWOD + bn + c4*4];
                }
            }
        }
        for (int c = 0; c < KC; c += 4){
            float4 A[8];
            #pragma unroll
            for (int ii = 0; ii < 8; ++ii) A[ii] = *(const float4*)&As[ty + 16*ii][c];
            float Bv0[8], Bv1[8], Bv2[8], Bv3[8];
            #pragma unroll
            for (int jj = 0; jj < 8; ++jj){
                Bv0[jj] = Bs[c+0][tx + 16*jj];
                Bv1[jj] = Bs[c+1][tx + 16*jj];
                Bv2[jj] = Bs[c+2][tx + 16*jj];
                Bv3[jj] = Bs[c+3][tx + 16*jj];
            }
            #pragma unroll
            for (int ii = 0; ii < 8; ++ii)
                #pragma unroll
                for (int jj = 0; jj < 8; ++jj){
                    acc[ii][jj] = fmaf(A[ii].x, Bv0[jj], acc[ii][jj]);
                    acc[ii][jj] = fmaf(A[ii].y, Bv1[jj], acc[ii][jj]);
                    acc[ii][jj] = fmaf(A[ii].z, Bv2[jj], acc[ii][jj]);
                    acc[ii][jj] = fmaf(A[ii].w, Bv3[jj], acc[ii][jj]);
                }
        }
        if (c0n >= CP) break;
        c0 = c0n; KC4 = KC4n;
    }

    #pragma unroll
    for (int jj = 0; jj < 8; ++jj){
        int n = bn + tx + 16*jj;
        int d = (n < D) ? n : n - D;
        float gg = g[d] * BN_INV;
        float bb = (n < D) ? 0.f : bias[d];
        #pragma unroll
        for (int ii = 0; ii < 8; ++ii)
            PQ[(long)(bi + ty + 16*ii) * TWOD + n] = fmaf(acc[ii][jj], gg, bb);
    }
}

// 64x64-tile variant for the small layers (full CU coverage on small grids).
__global__ __launch_bounds__(256) void gemm_pq64_kernel(
    const float* __restrict__ X, int CP, const float* __restrict__ Wcat,
    const float* __restrict__ g, const float* __restrict__ bias,
    int D, int TWOD, float* __restrict__ PQ)
{
    __shared__ __align__(16) float As[64][36];
    __shared__ __align__(16) float Bs[32][68];
    const int bi = blockIdx.x * 64;
    const int bn = blockIdx.y * 64;
    const int t  = threadIdx.x;
    const int tx = t & 15, ty = t >> 4;
    const int CP4 = CP / 4;
    const float4* xp = (const float4*)X;

    float acc[4][4] = {};
    float4 pa[2], pb[2];

    int c0 = 0;
    int KC4 = ((CP < 32) ? CP : 32) >> 2;
    #pragma unroll
    for (int s = 0; s < 2; ++s){
        int f = t + 256*s;
        if (f < 64*KC4){
            int r = f / KC4, c4 = f - r*KC4;
            pa[s] = xp[(long)(bi + r)*CP4 + c4];
        }
        if (f < 64*KC4){
            int r = f >> 4, c4 = f & 15;
            pb[s] = *(const float4*)&Wcat[(long)r * TWOD + bn + c4*4];
        }
    }

    for (;;){
        __syncthreads();
        #pragma unroll
        for (int s = 0; s < 2; ++s){
            int f = t + 256*s;
            if (f < 64*KC4){
                int r = f / KC4, c4 = f - r*KC4;
                *(float4*)&As[r][c4*4] = pa[s];
            }
            if (f < 64*KC4){
                int r = f >> 4, c4 = f & 15;
                *(float4*)&Bs[r][c4*4] = pb[s];
            }
        }
        __syncthreads();
        const int KC  = KC4 * 4;
        const int c0n = c0 + 32;
        int KC4n = 0;
        if (c0n < CP){
            KC4n = (((CP - c0n) < 32) ? (CP - c0n) : 32) >> 2;
            #pragma unroll
            for (int s = 0; s < 2; ++s){
                int f = t + 256*s;
                if (f < 64*KC4n){
                    int r = f / KC4n, c4 = f - r*KC4n;
                    pa[s] = xp[(long)(bi + r)*CP4 + (c0n >> 2) + c4];
                }
                if (f < 64*KC4n){
                    int r = f >> 4, c4 = f & 15;
                    pb[s] = *(const float4*)&Wcat[(long)(c0n + r) * TWOD + bn + c4*4];
                }
            }
        }
        for (int c = 0; c < KC; c += 4){
            float4 A[4];
            #pragma unroll
            for (int ii = 0; ii < 4; ++ii) A[ii] = *(const float4*)&As[ty + 16*ii][c];
            float B0[4], B1[4], B2[4], B3[4];
            #pragma unroll
            for (int jj = 0; jj < 4; ++jj){
                B0[jj] = Bs[c+0][tx + 16*jj];
                B1[jj] = Bs[c+1][tx + 16*jj];
                B2[jj] = Bs[c+2][tx + 16*jj];
                B3[jj] = Bs[c+3][tx + 16*jj];
            }
            #pragma unroll
            for (int ii = 0; ii < 4; ++ii)
                #pragma unroll
                for (int jj = 0; jj < 4; ++jj){
                    acc[ii][jj] = fmaf(A[ii].x, B0[jj], acc[ii][jj]);
                    acc[ii][jj] = fmaf(A[ii].y, B1[jj], acc[ii][jj]);
                    acc[ii][jj] = fmaf(A[ii].z, B2[jj], acc[ii][jj]);
                    acc[ii][jj] = fmaf(A[ii].w, B3[jj], acc[ii][jj]);
                }
        }
        if (c0n >= CP) break;
        c0 = c0n; KC4 = KC4n;
    }

    #pragma unroll
    for (int jj = 0; jj < 4; ++jj){
        int n = bn + tx + 16*jj;
        int d = (n < D) ? n : n - D;
        float gg = g[d] * BN_INV;
        float bb = (n < D) ? 0.f : bias[d];
        #pragma unroll
        for (int ii = 0; ii < 4; ++ii)
            PQ[(long)(bi + ty + 16*ii) * TWOD + n] = fmaf(acc[ii][jj], gg, bb);
    }
}

template<int D, int RPB>
__global__ __launch_bounds__(256) void gather_max_kernel(
    const float* __restrict__ PQ, const int* __restrict__ idx, int N,
    float* __restrict__ y, float* __restrict__ sqout)
{
    __shared__ int   lidx[RPB][KNN];
    __shared__ float sred[4];
    const int rb = blockIdx.x * RPB;
    const int t  = threadIdx.x;
    if (t < RPB * KNN) lidx[t / KNN][t % KNN] = idx[(long)rb * KNN + t];
    __syncthreads();

    const int r = t / D, d = t - r * D;
    const int row = rb + r;
    const long base = (long)(row / N) * N;
    const int TWOD = 2 * D;

    float q = PQ[(long)row * TWOD + D + d];
    float m = -INFINITY;
    #pragma unroll
    for (int k = 0; k < KNN; ++k){
        int j = lidx[r][k];
        m = fmaxf(m, PQ[(base + j) * TWOD + d]);
    }
    float val = leaky(m + q);
    y[(long)row * D + d] = val;

    float ss = val * val;
    #pragma unroll
    for (int off = 32; off; off >>= 1) ss += __shfl_xor(ss, off);
    if ((t & 63) == 0) sred[t >> 6] = ss;
    __syncthreads();
    if (d == 0){
        constexpr int WPR = D / 64;
        float s = 0.f;
        int w0 = (r * D) >> 6;
        #pragma unroll
        for (int w = 0; w < WPR; ++w) s += sred[w0 + w];
        sqout[row] = s;
    }
}

// ---------------- head as tiled GEMMs ----------------

__global__ __launch_bounds__(256) void head_gemm1_kernel(
    const float* __restrict__ x1, const float* __restrict__ x2,
    const float* __restrict__ x3, const float* __restrict__ x4,
    const float* __restrict__ Wc5, const float* __restrict__ g5,
    const float* __restrict__ b5, float* __restrict__ gf, int R)
{
    __shared__ __align__(16) float As[64][68];
    __shared__ __align__(16) float Bs[64][68];
    const int bi = blockIdx.x * 64;
    const int bn = blockIdx.y * 64;
    const int t  = threadIdx.x;
    const int tx = t & 15, ty = t >> 4;

    float acc[4][4] = {};

    #pragma unroll 1
    for (int kc = 0; kc < 8; ++kc){
        const float* src; int ld, coff;
        if      (kc == 0){ src = x1; ld = 64;  coff = 0; }
        else if (kc == 1){ src = x2; ld = 64;  coff = 0; }
        else if (kc <  4){ src = x3; ld = 128; coff = (kc-2)*64; }
        else             { src = x4; ld = 256; coff = (kc-4)*64; }
        __syncthreads();
        for (int f = t; f < 64*16; f += 256){
            int r = f >> 4, c4 = f & 15;
            *(float4*)&As[r][c4*4] = *(const float4*)&src[(long)(bi + r)*ld + coff + c4*4];
            *(float4*)&Bs[r][c4*4] = *(const float4*)&Wc5[(long)(kc*64 + r)*128 + bn + c4*4];
        }
        __syncthreads();
        for (int c = 0; c < 64; c += 4){
            float4 A[4];
            #pragma unroll
            for (int ii = 0; ii < 4; ++ii) A[ii] = *(const float4*)&As[ty + 16*ii][c];
            float B0[4], B1[4], B2[4], B3[4];
            #pragma unroll
            for (int jj = 0; jj < 4; ++jj){
                B0[jj] = Bs[c+0][tx + 16*jj];
                B1[jj] = Bs[c+1][tx + 16*jj];
                B2[jj] = Bs[c+2][tx + 16*jj];
                B3[jj] = Bs[c+3][tx + 16*jj];
            }
            #pragma unroll
            for (int ii = 0; ii < 4; ++ii)
                #pragma unroll
                for (int jj = 0; jj < 4; ++jj){
                    acc[ii][jj] = fmaf(A[ii].x, B0[jj], acc[ii][jj]);
                    acc[ii][jj] = fmaf(A[ii].y, B1[jj], acc[ii][jj]);
                    acc[ii][jj] = fmaf(A[ii].z, B2[jj], acc[ii][jj]);
                    acc[ii][jj] = fmaf(A[ii].w, B3[jj], acc[ii][jj]);
                }
        }
    }

    #pragma unroll
    for (int jj = 0; jj < 4; ++jj){
        int n = bn + tx + 16*jj;
        float gg = g5[n] * BN_INV, bb = b5[n];
        #pragma unroll
        for (int ii = 0; ii < 4; ++ii)
            gf[(long)(bi + ty + 16*ii)*128 + n] = leaky(fmaf(acc[ii][jj], gg, bb));
    }
}

__global__ __launch_bounds__(256) void head_lngemm_kernel(
    const float* __restrict__ hin, const float* __restrict__ W,
    const float* __restrict__ bo, const float* __restrict__ lg,
    const float* __restrict__ lb, float* __restrict__ hout, int R)
{
    __shared__ __align__(16) float As[64][68];
    __shared__ __align__(16) float Bs[64][132];
    const int bi = blockIdx.x * 64;
    const int t  = threadIdx.x;
    const int tx = t & 15, ty = t >> 4;

    float acc[4][8] = {};

    #pragma unroll 1
    for (int kc = 0; kc < 2; ++kc){
        __syncthreads();
        for (int f = t; f < 64*16; f += 256){
            int r = f >> 4, c4 = f & 15;
            *(float4*)&As[r][c4*4] = *(const float4*)&hin[(long)(bi + r)*128 + kc*64 + c4*4];
        }
        for (int f = t; f < 64*32; f += 256){
            int r = f >> 5, c4 = f & 31;
            *(float4*)&Bs[r][c4*4] = *(const float4*)&W[(long)(kc*64 + r)*128 + c4*4];
        }
        __syncthreads();
        for (int c = 0; c < 64; c += 4){
            float4 A[4];
            #pragma unroll
            for (int ii = 0; ii < 4; ++ii) A[ii] = *(const float4*)&As[ty + 16*ii][c];
            float B0[8], B1[8], B2[8], B3[8];
            #pragma unroll
            for (int jj = 0; jj < 8; ++jj){
                B0[jj] = Bs[c+0][tx + 16*jj];
                B1[jj] = Bs[c+1][tx + 16*jj];
                B2[jj] = Bs[c+2][tx + 16*jj];
                B3[jj] = Bs[c+3][tx + 16*jj];
            }
            #pragma unroll
            for (int ii = 0; ii < 4; ++ii)
                #pragma unroll
                for (int jj = 0; jj < 8; ++jj){
                    acc[ii][jj] = fmaf(A[ii].x, B0[jj], acc[ii][jj]);
                    acc[ii][jj] = fmaf(A[ii].y, B1[jj], acc[ii][jj]);
                    acc[ii][jj] = fmaf(A[ii].z, B2[jj], acc[ii][jj]);
                    acc[ii][jj] = fmaf(A[ii].w, B3[jj], acc[ii][jj]);
                }
        }
    }

    float bon[8], lgn[8], lbn[8];
    #pragma unroll
    for (int jj = 0; jj < 8; ++jj){
        int n = tx + 16*jj;
        bon[jj] = bo[n]; lgn[jj] = lg[n]; lbn[jj] = lb[n];
    }
    #pragma unroll
    for (int ii = 0; ii < 4; ++ii){
        float s1 = 0.f, s2 = 0.f;
        #pragma unroll
        for (int jj = 0; jj < 8; ++jj){
            float a = acc[ii][jj] + bon[jj];
            acc[ii][jj] = a;
            s1 += a; s2 += a*a;
        }
        #pragma unroll
        for (int off = 8; off; off >>= 1){
            s1 += __shfl_xor(s1, off);
            s2 += __shfl_xor(s2, off);
        }
        float m = s1 * (1.f/128.f);
        float v = s2 * (1.f/128.f) - m*m;
        float rinv = rsqrtf(v + 1e-5f);
        long r = bi + ty + 16*ii;
        #pragma unroll
        for (int jj = 0; jj < 8; ++jj)
            hout[r*128 + tx + 16*jj] = leaky((acc[ii][jj] - m) * rinv * lgn[jj] + lbn[jj]);
    }
}

#define OP 16
__global__ __launch_bounds__(256) void head_out_kernel(
    const float* __restrict__ h, const float* __restrict__ feats,
    const float* __restrict__ Wo3, const float* __restrict__ bo3,
    float* __restrict__ out, int R)
{
    __shared__ __align__(16) float hs[OP][132];
    __shared__ float f14[OP][14];
    const int t  = threadIdx.x;
    const long p0 = (long)blockIdx.x * OP;

    for (int f = t; f < OP*32; f += 256){
        int r = f >> 5, c4 = f & 31;
        *(float4*)&hs[r][c4*4] = *(const float4*)&h[(p0 + r)*128 + c4*4];
    }
    if (t < OP*14) f14[t/14][t%14] = feats[(p0 + t/14)*116 + t%14];
    __syncthreads();

    const int w = t >> 6, l = t & 63;
    if (l < 38){
        float o[4];
        float bt = bo3[l];
        #pragma unroll
        for (int pp = 0; pp < 4; ++pp) o[pp] = bt;
        for (int c = 0; c < 128; ++c){
            float wv = Wo3[c*38 + l];
            #pragma unroll
            for (int pp = 0; pp < 4; ++pp)
                o[pp] = fmaf(hs[w*4 + pp][c], wv, o[pp]);
        }
        #pragma unroll
        for (int pp = 0; pp < 4; ++pp){
            int p = w*4 + pp;
            float val = o[pp] + ((l < 14) ? f14[p][l] : 0.f);
            out[(p0 + p)*38 + l] = val;
        }
    }
}

// ---------------- fallback kNN + EdgeConv + head (known-good, N != 4096) ----------------
__global__ __launch_bounds__(256) void knn_kernel(
    const float* __restrict__ x, int N, int CP4, int* __restrict__ idx_out)
{
    __shared__ float4 xi4[32];
    __shared__ float drow[4096];
    __shared__ float rv[4];
    __shared__ int   ri[4];

    int row = blockIdx.x;
    int b = row / N;
    int t = threadIdx.x;
    const float4* xp = (const float4*)x;

    if (t < CP4) xi4[t] = xp[(long)row * CP4 + t];
    __syncthreads();

    long bb = (long)b * N * CP4;
    for (int j = t; j < N; j += 256){
        const float4* p = xp + bb + (long)j * CP4;
        float acc = 0.f;
        #pragma unroll 4
        for (int c = 0; c < CP4; ++c){
            float4 xv = p[c], yv = xi4[c];
            float dx = xv.x - yv.x, dy = xv.y - yv.y;
            float dz = xv.z - yv.z, dw = xv.w - yv.w;
            acc += dx*dx + dy*dy + dz*dz + dw*dw;
        }
        drow[j] = -acc;
    }
    __syncthreads();

    for (int it = 0; it < KNN; ++it){
        float bv = -INFINITY; int bi = N;
        for (int j = t; j < N; j += 256){
            float v = drow[j];
            if (v > bv){ bv = v; bi = j; }
        }
        #pragma unroll
        for (int off = 32; off > 0; off >>= 1){
            float ov = __shfl_xor(bv, off);
            int   oi = __shfl_xor(bi, off);
            if (ov > bv || (ov == bv && oi < bi)){ bv = ov; bi = oi; }
        }
        if ((t & 63) == 0){ rv[t >> 6] = bv; ri[t >> 6] = bi; }
        __syncthreads();
        if (t == 0){
            float fv = rv[0]; int fi = ri[0];
            #pragma unroll
            for (int w = 1; w < 4; ++w){
                if (rv[w] > fv || (rv[w] == fv && ri[w] < fi)){ fv = rv[w]; fi = ri[w]; }
            }
            idx_out[(long)row * KNN + it] = fi;
            drow[fi] = -INFINITY;
        }
        __syncthreads();
    }
}

template<int D, int KPT>
__global__ __launch_bounds__(256) void edge_conv_kernel(
    const float* __restrict__ x, int N, int C, int CP,
    const float* __restrict__ W, const float* __restrict__ g,
    const float* __restrict__ bias, const int* __restrict__ idx,
    float* __restrict__ y, float* __restrict__ sqout)
{
    __shared__ float xi[128];
    __shared__ float nbr[KNN * 128];
    __shared__ float t2[D];
    __shared__ unsigned um[D];
    __shared__ float sred[4];

    int row = blockIdx.x;
    int b = row / N;
    int t = threadIdx.x;

    for (int c = t; c < C; c += 256) xi[c] = x[(long)row * CP + c];
    for (int kk = 0; kk < KNN; ++kk){
        int j = idx[(long)row * KNN + kk];
        long nb = ((long)b * N + j) * CP;
        for (int c = t; c < C; c += 256) nbr[kk * C + c] = x[nb + c];
    }
    __syncthreads();

    for (int d = t; d < D; d += 256){
        float s = 0.f;
        for (int c = 0; c < C; ++c) s += xi[c] * W[(C + c) * D + d];
        t2[d] = s; um[d] = 0u;
    }
    __syncthreads();

    const int d  = t % D;
    const int kg = t / D;
    float s[KPT];
    #pragma unroll
    for (int q = 0; q < KPT; ++q) s[q] = t2[d];

    const float* nb0 = &nbr[(kg * KPT) * C];
    for (int c = 0; c < C; ++c){
        float w   = W[c * D + d];
        float xic = xi[c];
        #pragma unroll
        for (int q = 0; q < KPT; ++q)
            s[q] += (nb0[q * C + c] - xic) * w;
    }
    float g_ = g[d] * BN_INV, b_ = bias[d];
    float m = -INFINITY;
    #pragma unroll
    for (int q = 0; q < KPT; ++q)
        m = fmaxf(m, leaky(s[q] * g_ + b_));
    atomicMax(&um[d], f2o(m));
    __syncthreads();

    float ss = 0.f;
    for (int dd = t; dd < D; dd += 256){
        float val = o2f(um[dd]);
        y[(long)row * D + dd] = val;
        ss += val * val;
    }
    #pragma unroll
    for (int off = 32; off; off >>= 1) ss += __shfl_xor(ss, off);
    if ((t & 63) == 0) sred[t >> 6] = ss;
    __syncthreads();
    if (t == 0) sqout[row] = sred[0] + sred[1] + sred[2] + sred[3];
}

#define HP 8
__global__ __launch_bounds__(128) void head_kernel(
    const float* __restrict__ x1, const float* __restrict__ x2,
    const float* __restrict__ x3, const float* __restrict__ x4,
    const float* __restrict__ feats,
    const float* __restrict__ Wc5, const float* __restrict__ g5, const float* __restrict__ b5,
    const float* __restrict__ Wo1, const float* __restrict__ bo1,
    const float* __restrict__ lg1, const float* __restrict__ lb1,
    const float* __restrict__ Wo2, const float* __restrict__ bo2,
    const float* __restrict__ lg2, const float* __restrict__ lb2,
    const float* __restrict__ Wo3, const float* __restrict__ bo3,
    float* __restrict__ out, int N, int R)
{
    __shared__ __align__(16) float cat[HP][520];
    __shared__ __align__(16) float hb[HP][132];
    __shared__ float wsum[2][HP], wsq[2][HP];
    __shared__ float f14[HP][14];

    const int t = threadIdx.x;
    const long p0 = (long)blockIdx.x * HP;
    const int wid = t >> 6;

    long rows[HP];
    #pragma unroll
    for (int p = 0; p < HP; ++p){
        long row = p0 + p; if (row >= R) row = R - 1;
        rows[p] = row;
        cat[p][t]       = (t < 64) ? x1[row*64 + t] : x2[row*64 + (t-64)];
        cat[p][128 + t] = x3[row*128 + t];
        cat[p][256 + t] = x4[row*256 + t];
        cat[p][384 + t] = x4[row*256 + 128 + t];
        if (t < 14) f14[p][t] = feats[row*116 + t];
    }
    __syncthreads();

    const float g5t = g5[t] * BN_INV, b5t = b5[t];
    float acc[HP];
    #pragma unroll
    for (int p = 0; p < HP; ++p) acc[p] = 0.f;
    for (int c4 = 0; c4 < 128; ++c4){
        float w0 = Wc5[(4*c4+0)*128 + t];
        float w1 = Wc5[(4*c4+1)*128 + t];
        float w2 = Wc5[(4*c4+2)*128 + t];
        float w3 = Wc5[(4*c4+3)*128 + t];
        #pragma unroll
        for (int p = 0; p < HP; ++p){
            float4 cv = *(const float4*)&cat[p][4*c4];
            acc[p] = fmaf(cv.x, w0, acc[p]);
            acc[p] = fmaf(cv.y, w1, acc[p]);
            acc[p] = fmaf(cv.z, w2, acc[p]);
            acc[p] = fmaf(cv.w, w3, acc[p]);
        }
    }
    #pragma unroll
    for (int p = 0; p < HP; ++p) hb[p][t] = leaky(fmaf(acc[p], g5t, b5t));
    __syncthreads();

    for (int layer = 0; layer < 2; ++layer){
        const float* W  = layer ? Wo2 : Wo1;
        const float* bo = layer ? bo2 : bo1;
        const float* lg = layer ? lg2 : lg1;
        const float* lb = layer ? lb2 : lb1;
        float a2[HP];
        float bot = bo[t];
        #pragma unroll
        for (int p = 0; p < HP; ++p) a2[p] = bot;
        for (int c4 = 0; c4 < 32; ++c4){
            float w0 = W[(4*c4+0)*128 + t];
            float w1 = W[(4*c4+1)*128 + t];
            float w2 = W[(4*c4+2)*128 + t];
            float w3 = W[(4*c4+3)*128 + t];
            #pragma unroll
            for (int p = 0; p < HP; ++p){
                float4 hv = *(const float4*)&hb[p][4*c4];
                a2[p] = fmaf(hv.x, w0, a2[p]);
                a2[p] = fmaf(hv.y, w1, a2[p]);
                a2[p] = fmaf(hv.z, w2, a2[p]);
                a2[p] = fmaf(hv.w, w3, a2[p]);
            }
        }
        #pragma unroll
        for (int p = 0; p < HP; ++p){
            float s1 = a2[p], s2 = a2[p]*a2[p];
            #pragma unroll
            for (int off = 32; off; off >>= 1){
                s1 += __shfl_xor(s1, off);
                s2 += __shfl_xor(s2, off);
            }
            if ((t & 63) == 0){ wsum[wid][p] = s1; wsq[wid][p] = s2; }
        }
        __syncthreads();
        float lgt = lg[t], lbt = lb[t];
        float hn[HP];
        #pragma unroll
        for (int p = 0; p < HP; ++p){
            float m  = (wsum[0][p] + wsum[1][p]) * (1.f/128.f);
            float v  = (wsq[0][p]  + wsq[1][p])  * (1.f/128.f) - m*m;
            float dm = a2[p] - m;
            hn[p] = leaky(dm * rsqrtf(v + 1e-5f) * lgt + lbt);
        }
        __syncthreads();
        #pragma unroll
        for (int p = 0; p < HP; ++p) hb[p][t] = hn[p];
        __syncthreads();
    }

    if (t < 38){
        float o[HP];
        float bt = bo3[t];
        #pragma unroll
        for (int p = 0; p < HP; ++p) o[p] = bt;
        for (int c = 0; c < 128; ++c){
            float w = Wo3[c*38 + t];
            #pragma unroll
            for (int p = 0; p < HP; ++p) o[p] = fmaf(hb[p][c], w, o[p]);
        }
        #pragma unroll
        for (int p = 0; p < HP; ++p){
            float val = o[p] + ((t < 14) ? f14[p][t] : 0.f);
            out[rows[p]*38 + t] = val;
        }
    }
}

extern "C" void kernel_launch(void* const* d_in, const int* in_sizes, int n_in,
                              void* d_out, int out_size, void* d_ws, size_t ws_size,
                              hipStream_t stream)
{
    const float* xyz  = (const float*)d_in[0];
    const float* scal = (const float*)d_in[1];
    const float* rot  = (const float*)d_in[2];
    const float* opac = (const float*)d_in[3];
    const float* colr = (const float*)d_in[4];
    const float* pose = (const float*)d_in[5];
    const float* lbs  = (const float*)d_in[6];
    const float* Wc1 = (const float*)d_in[7];  const float* g1 = (const float*)d_in[8];  const float* b1 = (const float*)d_in[9];
    const float* Wc2 = (const float*)d_in[10]; const float* g2 = (const float*)d_in[11]; const float* b2 = (const float*)d_in[12];
    const float* Wc3 = (const float*)d_in[13]; const float* g3 = (const float*)d_in[14]; const float* b3 = (const float*)d_in[15];
    const float* Wc4 = (const float*)d_in[16]; const float* g4 = (const float*)d_in[17]; const float* b4 = (const float*)d_in[18];
    const float* Wc5 = (const float*)d_in[19]; const float* g5 = (const float*)d_in[20]; const float* b5 = (const float*)d_in[21];
    const float* Wo1 = (const float*)d_in[22]; const float* bo1 = (const float*)d_in[23];
    const float* lg1 = (const float*)d_in[24]; const float* lb1 = (const float*)d_in[25];
    const float* Wo2 = (const float*)d_in[26]; const float* bo2 = (const float*)d_in[27];
    const float* lg2 = (const float*)d_in[28]; const float* lb2 = (const float*)d_in[29];
    const float* Wo3 = (const float*)d_in[30]; const float* bo3 = (const float*)d_in[31];

    const int N = in_sizes[0] / 3;      // 4096
    const int B = in_sizes[5] / 75;     // 2
    const int R = B * N;

    char* ws = (char*)d_ws;
    size_t o = 0;
    float* feats = (float*)(ws + o); o += (size_t)R * 116 * 4;
    float* x1    = (float*)(ws + o); o += (size_t)R * 64  * 4;
    float* x2    = (float*)(ws + o); o += (size_t)R * 64  * 4;
    float* x3    = (float*)(ws + o); o += (size_t)R * 128 * 4;
    float* x4    = (float*)(ws + o); o += (size_t)R * 256 * 4;
    int*   idx   = (int*)  (ws + o); o += (size_t)R * KNN * 4;
    float* sq    = (float*)(ws + o); o += (size_t)R * 4;
    float* Wcat  = (float*)(ws + o); o += (size_t)104960 * 4;
    float* G     = (float*)(ws + o);
    float* PQ    = G;                   // alias: stream-ordered reuse
    float* gf    = G;                   // head temps alias G (free after last gather)
    float* h1    = G + (size_t)R * 128;
    float* h2    = G + (size_t)R * 256;
    size_t need  = o + (size_t)B * N * N * 4;

    const bool fast = (N == 4096) && (ws_size >= need);

    build_feats_kernel<<<R, 128, 0, stream>>>(xyz, scal, rot, opac, colr, pose, lbs, feats, sq, N);

    if (fast){
        const int NT = 32;                       // 4096/128 tiles
        dim3 gg(NT*(NT+1)/2, 1, B);              // packed upper triangle
        float* Wcat1 = Wcat;
        float* Wcat2 = Wcat + 14848;
        float* Wcat3 = Wcat + 23040;
        float* Wcat4 = Wcat + 39424;

        prep_all_wcat_kernel<<<(104960 + 255)/256, 256, 0, stream>>>(Wc1, Wc2, Wc3, Wc4, Wcat);

        // L1: C=113 (CP=116), D=64
        dist_gemm_kernel<116><<<gg, 256, 0, stream>>>(feats, N, 116, G);
        topk_kernel<<<R, 256, 0, stream>>>(G, sq, N, idx);
        gemm_pq64_kernel<<<dim3(R/64, 2), 256, 0, stream>>>(feats, 116, Wcat1, g1, b1, 64, 128, PQ);
        gather_max_kernel<64, 4><<<R/4, 256, 0, stream>>>(PQ, idx, N, x1, sq);

        // L2: C=64, D=64
        dist_gemm_kernel<64><<<gg, 256, 0, stream>>>(x1, N, 64, G);
        topk_kernel<<<R, 256, 0, stream>>>(G, sq, N, idx);
        gemm_pq64_kernel<<<dim3(R/64, 2), 256, 0, stream>>>(x1, 64, Wcat2, g2, b2, 64, 128, PQ);
        gather_max_kernel<64, 4><<<R/4, 256, 0, stream>>>(PQ, idx, N, x2, sq);

        // L3: C=64, D=128
        dist_gemm_kernel<64><<<gg, 256, 0, stream>>>(x2, N, 64, G);
        topk_kernel<<<R, 256, 0, stream>>>(G, sq, N, idx);
        gemm_pq64_kernel<<<dim3(R/64, 4), 256, 0, stream>>>(x2, 64, Wcat3, g3, b3, 128, 256, PQ);
        gather_max_kernel<128, 2><<<R/2, 256, 0, stream>>>(PQ, idx, N, x3, sq);

        // L4: C=128, D=256
        dist_gemm_kernel<128><<<gg, 256, 0, stream>>>(x3, N, 128, G);
        topk_kernel<<<R, 256, 0, stream>>>(G, sq, N, idx);
        gemm_pq_kernel<<<dim3(R/128, 4), 256, 0, stream>>>(x3, 128, Wcat4, g4, b4, 256, 512, PQ);
        gather_max_kernel<256, 1><<<R, 256, 0, stream>>>(PQ, idx, N, x4, sq);

        // head: tiled GEMMs (gf/h1/h2 alias G, free after last gather)
        head_gemm1_kernel<<<dim3(R/64, 2), 256, 0, stream>>>(x1, x2, x3, x4, Wc5, g5, b5, gf, R);
        head_lngemm_kernel<<<R/64, 256, 0, stream>>>(gf, Wo1, bo1, lg1, lb1, h1, R);
        head_lngemm_kernel<<<R/64, 256, 0, stream>>>(h1, Wo2, bo2, lg2, lb2, h2, R);
        head_out_kernel<<<R/OP, 256, 0, stream>>>(h2, feats, Wo3, bo3, (float*)d_out, R);
    } else {
        knn_kernel<<<R, 256, 0, stream>>>(feats, N, 116/4, idx);
        edge_conv_kernel<64, 5><<<R, 256, 0, stream>>>(feats, N, 113, 116, Wc1, g1, b1, idx, x1, sq);
        knn_kernel<<<R, 256, 0, stream>>>(x1, N, 64/4, idx);
        edge_conv_kernel<64, 5><<<R, 256, 0, stream>>>(x1, N, 64, 64, Wc2, g2, b2, idx, x2, sq);
        knn_kernel<<<R, 256, 0, stream>>>(x2, N, 64/4, idx);
        edge_conv_kernel<128, 10><<<R, 256, 0, stream>>>(x2, N, 64, 64, Wc3, g3, b3, idx, x3, sq);
        knn_kernel<<<R, 256, 0, stream>>>(x3, N, 128/4, idx);
        edge_conv_kernel<256, 20><<<R, 256, 0, stream>>>(x3, N, 128, 128, Wc4, g4, b4, idx, x4, sq);

        head_kernel<<<(R + HP - 1)/HP, 128, 0, stream>>>(x1, x2, x3, x4, feats,
                                           Wc5, g5, b5, Wo1, bo1, lg1, lb1,
                                           Wo2, bo2, lg2, lb2, Wo3, bo3,
                                           (float*)d_out, N, R);
    }
}